// Round 6
// baseline (1528.804 us; speedup 1.0000x reference)
//
#include <hip/hip_runtime.h>

#define TPB 256
#define BSH 9                   // log2(nodes per bucket)
#define BNODES (1 << BSH)       // 512
#define BMASK (BNODES - 1)
#define SCAT_TPB 1024
#define STILE 16384             // edges per k_scat tile (64 KB stage)
#define EPT 16                  // edges per thread in k_scat (STILE/SCAT_TPB)
#define CAP 18432               // bucket segment capacity (mean 16384, +16 sigma)
#define NT 13                   // src tiles (200000 >> 14 -> 0..12)
#define TSH 14                  // src tile = 16384 nodes = 512 KB fp16 slice
#define ACST 17                 // LDS accumulator row stride (floats), odd -> bank spread
#define ACC_TPB 1024

typedef _Float16 half8 __attribute__((ext_vector_type(8)));
typedef _Float16 half2v __attribute__((ext_vector_type(2)));

// ---------------- init: gpos[b] = b*CAP, gsum = 0 ----------------
__global__ void k_init(int* __restrict__ gpos, float* __restrict__ gsum,
                       int nbuck, int gsum_len) {
  int i = blockIdx.x * blockDim.x + threadIdx.x;
  if (i < nbuck) gpos[i] = i * CAP;
  if (i < gsum_len) gsum[i] = 0.0f;
}

// ---------------- tile-sort scatter into segmented buckets ----------------
__global__ void __launch_bounds__(SCAT_TPB)
k_scat(const int* __restrict__ src, const int* __restrict__ dst,
       int* __restrict__ gpos, unsigned* __restrict__ bucketed,
       int E, int nbuck) {
  __shared__ unsigned stage[STILE];   // 64 KB, bucket-sorted tile
  __shared__ int cnt[512];
  __shared__ int runp[512];
  __shared__ int lofs[513];
  __shared__ int base[512];
  __shared__ int wsum[16];
  int t = threadIdx.x;
  int ts = blockIdx.x * STILE;
  int count = min(STILE, E - ts);
  int d[EPT], s[EPT];

  for (int i = t; i < nbuck; i += SCAT_TPB) cnt[i] = 0;
  __syncthreads();
  // pass A: load tile into registers + count
#pragma unroll
  for (int j = 0; j < EPT; ++j) {
    int i = j * SCAT_TPB + t;
    if (i < count) {
      d[j] = dst[ts + i];
      s[j] = src[ts + i];
      atomicAdd(&cnt[d[j] >> BSH], 1);
    }
  }
  __syncthreads();
  // scan + global reservation (one atomic per non-empty bucket)
  {
    int v = (t < nbuck) ? cnt[t] : 0;
    int lane = t & 63, wid = t >> 6;
    int inc = v;
    for (int dd = 1; dd < 64; dd <<= 1) {
      int u = __shfl_up(inc, dd, 64);
      if (lane >= dd) inc += u;
    }
    if (lane == 63) wsum[wid] = inc;
    __syncthreads();
    int woff = 0;
    for (int w = 0; w < wid; ++w) woff += wsum[w];
    int excl = woff + inc - v;
    if (t < nbuck) {
      lofs[t] = excl;
      runp[t] = excl;
      base[t] = v ? atomicAdd(&gpos[t], v) : 0;
    }
    if (t == 0) lofs[nbuck] = count;
  }
  __syncthreads();
  // pass B: place registers into stage (bucket-sorted)
#pragma unroll
  for (int j = 0; j < EPT; ++j) {
    int i = j * SCAT_TPB + t;
    if (i < count) {
      int b = d[j] >> BSH;
      int p = atomicAdd(&runp[b], 1);
      stage[p] = ((unsigned)(d[j] & BMASK) << 18) | (unsigned)s[j];
    }
  }
  __syncthreads();
  // pass C: per-wave bucket-run copy (sequential stage reads / global writes)
  {
    int lane = t & 63, wid = t >> 6;
    for (int b = wid; b < nbuck; b += SCAT_TPB / 64) {
      int s0 = lofs[b], s1 = lofs[b + 1];
      int gb = base[b];
      for (int i = s0 + lane; i < s1; i += 64)
        bucketed[gb + (i - s0)] = stage[i];
    }
  }
}

// ---------------- per-bucket: degree/dinv + src-tile-major edge reorder ----------------
// Output edges2: bucket segment reordered so all edges with src-tile 0 come
// first, then tile 1, ... (13 segments of ~1260 edges). The accumulate kernels
// walk this list linearly -> all co-resident blocks touch the same 512 KB
// table slice at the same time (L2-resident, densely used).
__global__ void __launch_bounds__(ACC_TPB)
k_tile(const unsigned* __restrict__ bucketed, const int* __restrict__ gpos,
       unsigned* __restrict__ edges2, float* __restrict__ dinv, int N) {
  int b = blockIdx.x;
  int t = threadIdx.x;
  int lane = t & 63;
  int beg = b * CAP;
  int end = gpos[b];
  int total = end - beg;
  __shared__ int deg[BNODES];
  __shared__ int tcnt[NT];
  __shared__ int trun[NT];
  if (t < BNODES) deg[t] = 0;
  if (t < NT) tcnt[t] = 0;
  __syncthreads();
  // pass 1: count node degrees + tile populations (wave-aggregated)
  int iters = (total + ACC_TPB - 1) / ACC_TPB;
  int wcnt = 0;  // lane k (<NT) accumulates tile-k count for this wave
  for (int it = 0; it < iters; ++it) {
    int i = beg + it * ACC_TPB + t;
    bool act = i < end;
    unsigned p = act ? bucketed[i] : 0u;
    if (act) atomicAdd(&deg[(p >> 18) & BMASK], 1);
    int tile = (int)(p & 0x3ffffu) >> TSH;
#pragma unroll
    for (int k = 0; k < NT; ++k) {
      unsigned long long m = __ballot(act && tile == k);
      int c = __popcll(m);
      if (lane == k) wcnt += c;
    }
  }
  if (lane < NT) atomicAdd(&tcnt[lane], wcnt);
  __syncthreads();
  if (t == 0) {
    int run = 0;
    for (int k = 0; k < NT; ++k) { trun[k] = run; run += tcnt[k]; }
  }
  if (t < BNODES) {
    int n = (b << BSH) + t;
    if (n < N) dinv[n] = rsqrtf((float)deg[t] + 1.0f);
  }
  __syncthreads();
  // pass 2: scatter into tile-major order (wave-aggregated position reservation)
  for (int it = 0; it < iters; ++it) {
    int i = beg + it * ACC_TPB + t;
    bool act = i < end;
    unsigned p = act ? bucketed[i] : 0u;
    int tile = (int)(p & 0x3ffffu) >> TSH;
#pragma unroll
    for (int k = 0; k < NT; ++k) {
      unsigned long long m = __ballot(act && tile == k);
      if (!m) continue;
      int leader = __ffsll((long long)m) - 1;
      int base = 0;
      if (lane == leader) base = atomicAdd(&trun[k], __popcll(m));
      base = __shfl(base, leader, 64);
      if (act && tile == k) {
        int pos = base + __popcll(m & ((1ull << lane) - 1ull));
        edges2[beg + pos] = p;
      }
    }
  }
}

// ---------------- hs1 = fp16( dinv * (x @ W1) ) ----------------
__global__ void k_xw1(const float* __restrict__ x, const float* __restrict__ W1,
                      const float* __restrict__ dinv, _Float16* __restrict__ hs,
                      int n_nodes) {
  int n = blockIdx.x * blockDim.x + threadIdx.x;
  if (n >= n_nodes) return;
  const float4* xr = reinterpret_cast<const float4*>(x + (size_t)n * 128);
  float s[16];
#pragma unroll
  for (int c = 0; c < 16; ++c) s[c] = 0.0f;
#pragma unroll 4
  for (int k4 = 0; k4 < 32; ++k4) {
    float4 xv = xr[k4];
    const float* w = W1 + k4 * 64;  // uniform address -> scalar loads
#pragma unroll
    for (int c = 0; c < 16; ++c) s[c] = fmaf(xv.x, w[c], s[c]);
#pragma unroll
    for (int c = 0; c < 16; ++c) s[c] = fmaf(xv.y, w[16 + c], s[c]);
#pragma unroll
    for (int c = 0; c < 16; ++c) s[c] = fmaf(xv.z, w[32 + c], s[c]);
#pragma unroll
    for (int c = 0; c < 16; ++c) s[c] = fmaf(xv.w, w[48 + c], s[c]);
  }
  float dn = dinv[n];
  half8 v0, v1;
#pragma unroll
  for (int j = 0; j < 8; ++j) v0[j] = (_Float16)(dn * s[j]);
#pragma unroll
  for (int j = 0; j < 8; ++j) v1[j] = (_Float16)(dn * s[8 + j]);
  half8* hp = reinterpret_cast<half8*>(hs + (size_t)n * 16);
  hp[0] = v0;
  hp[1] = v1;
}

// ---------------- accumulate one bucket's edges into LDS (tile-phased) ----------------
__device__ __forceinline__ void acc_edges(const _Float16* __restrict__ tab,
                                          const unsigned* __restrict__ edges2,
                                          float* __restrict__ acc,
                                          int beg, int end, int g, int c2) {
  int i = beg + g;
  for (; i + 384 < end; i += 512) {
    unsigned p0 = edges2[i];
    unsigned p1 = edges2[i + 128];
    unsigned p2 = edges2[i + 256];
    unsigned p3 = edges2[i + 384];
    half2v f0 = *reinterpret_cast<const half2v*>(tab + (size_t)(p0 & 0x3ffffu) * 16 + c2 * 2);
    half2v f1 = *reinterpret_cast<const half2v*>(tab + (size_t)(p1 & 0x3ffffu) * 16 + c2 * 2);
    half2v f2 = *reinterpret_cast<const half2v*>(tab + (size_t)(p2 & 0x3ffffu) * 16 + c2 * 2);
    half2v f3 = *reinterpret_cast<const half2v*>(tab + (size_t)(p3 & 0x3ffffu) * 16 + c2 * 2);
    int i0 = (p0 >> 18) & BMASK, i1 = (p1 >> 18) & BMASK;
    int i2 = (p2 >> 18) & BMASK, i3 = (p3 >> 18) & BMASK;
    atomicAdd(&acc[i0 * ACST + c2 * 2 + 0], (float)f0[0]);
    atomicAdd(&acc[i0 * ACST + c2 * 2 + 1], (float)f0[1]);
    atomicAdd(&acc[i1 * ACST + c2 * 2 + 0], (float)f1[0]);
    atomicAdd(&acc[i1 * ACST + c2 * 2 + 1], (float)f1[1]);
    atomicAdd(&acc[i2 * ACST + c2 * 2 + 0], (float)f2[0]);
    atomicAdd(&acc[i2 * ACST + c2 * 2 + 1], (float)f2[1]);
    atomicAdd(&acc[i3 * ACST + c2 * 2 + 0], (float)f3[0]);
    atomicAdd(&acc[i3 * ACST + c2 * 2 + 1], (float)f3[1]);
  }
  for (; i < end; i += 128) {
    unsigned p = edges2[i];
    int idx = (p >> 18) & BMASK;
    half2v f = *reinterpret_cast<const half2v*>(tab + (size_t)(p & 0x3ffffu) * 16 + c2 * 2);
    atomicAdd(&acc[idx * ACST + c2 * 2 + 0], (float)f[0]);
    atomicAdd(&acc[idx * ACST + c2 * 2 + 1], (float)f[1]);
  }
}

// ---------------- conv1: LDS-accumulate + self + relu + W2 -> H2 ----------------
__global__ void __launch_bounds__(ACC_TPB)
k_acc1(const _Float16* __restrict__ hs1, const unsigned* __restrict__ edges2,
       const int* __restrict__ gpos, const float* __restrict__ dinv,
       const float* __restrict__ b1, const float* __restrict__ W2,
       _Float16* __restrict__ hs2, int N) {
  int b = blockIdx.x;
  int t = threadIdx.x;
  int g = t >> 3, c2 = t & 7;
  __shared__ float acc[BNODES * ACST];   // 34.8 KB
  for (int i = t; i < BNODES * ACST; i += ACC_TPB) acc[i] = 0.0f;
  __syncthreads();
  acc_edges(hs1, edges2, acc, b * CAP, gpos[b], g, c2);
  __syncthreads();
  int n0 = b << BSH;
  for (int nn = g; nn < BNODES; nn += ACC_TPB / 8) {
    int n = n0 + nn;
    if (n < N) {
      half2v selfr = *reinterpret_cast<const half2v*>(hs1 + (size_t)n * 16 + c2 * 2);
      float a0 = acc[nn * ACST + c2 * 2 + 0] + (float)selfr[0];
      float a1 = acc[nn * ACST + c2 * 2 + 1] + (float)selfr[1];
      float dn = dinv[n];
      float h1a = fmaxf(fmaf(dn, a0, b1[c2 * 2 + 0]), 0.0f);
      float h1b = fmaxf(fmaf(dn, a1, b1[c2 * 2 + 1]), 0.0f);
      float oa = 0.0f, ob = 0.0f;
#pragma unroll
      for (int j = 0; j < 8; ++j) {
        float hk0 = __shfl(h1a, j, 8);
        float hk1 = __shfl(h1b, j, 8);
        oa = fmaf(hk0, W2[(2 * j) * 16 + c2 * 2 + 0], oa);
        ob = fmaf(hk0, W2[(2 * j) * 16 + c2 * 2 + 1], ob);
        oa = fmaf(hk1, W2[(2 * j + 1) * 16 + c2 * 2 + 0], oa);
        ob = fmaf(hk1, W2[(2 * j + 1) * 16 + c2 * 2 + 1], ob);
      }
      half2v outv;
      outv[0] = (_Float16)(dn * oa);
      outv[1] = (_Float16)(dn * ob);
      *reinterpret_cast<half2v*>(hs2 + (size_t)n * 16 + c2 * 2) = outv;
    }
  }
}

// ---------------- conv2: LDS-accumulate + self + bias + pool -> gsum ----------------
__global__ void __launch_bounds__(ACC_TPB)
k_acc2(const _Float16* __restrict__ hs2, const unsigned* __restrict__ edges2,
       const int* __restrict__ gpos, const float* __restrict__ dinv,
       const float* __restrict__ b2, const int* __restrict__ batch,
       float* __restrict__ gsum, int N) {
  int b = blockIdx.x;
  int t = threadIdx.x;
  int g = t >> 3, c2 = t & 7;
  __shared__ float acc[BNODES * ACST];
  __shared__ float gacc[8 * 16];
  __shared__ int sg0;
  for (int i = t; i < BNODES * ACST; i += ACC_TPB) acc[i] = 0.0f;
  if (t < 128) gacc[t] = 0.0f;
  int n0 = b << BSH;
  if (t == 0) sg0 = batch[n0];
  __syncthreads();
  acc_edges(hs2, edges2, acc, b * CAP, gpos[b], g, c2);
  __syncthreads();
  int g0 = sg0;
  for (int nn = g; nn < BNODES; nn += ACC_TPB / 8) {
    int n = n0 + nn;
    if (n < N) {
      half2v selfr = *reinterpret_cast<const half2v*>(hs2 + (size_t)n * 16 + c2 * 2);
      float a0 = acc[nn * ACST + c2 * 2 + 0] + (float)selfr[0];
      float a1 = acc[nn * ACST + c2 * 2 + 1] + (float)selfr[1];
      float dn = dinv[n];
      float v0 = fmaf(dn, a0, b2[c2 * 2 + 0]);
      float v1 = fmaf(dn, a1, b2[c2 * 2 + 1]);
      int gg = batch[n];
      int rel = gg - g0;
      if (rel < 8) {
        atomicAdd(&gacc[rel * 16 + c2 * 2 + 0], v0);
        atomicAdd(&gacc[rel * 16 + c2 * 2 + 1], v1);
      } else {
        unsafeAtomicAdd(&gsum[(size_t)gg * 16 + c2 * 2 + 0], v0);
        unsafeAtomicAdd(&gsum[(size_t)gg * 16 + c2 * 2 + 1], v1);
      }
    }
  }
  __syncthreads();
  if (t < 128) {
    float v = gacc[t];
    if (v != 0.0f)
      unsafeAtomicAdd(&gsum[(size_t)(g0 + (t >> 4)) * 16 + (t & 15)], v);
  }
}

// ---------------- mean + FC head ----------------
__device__ __forceinline__ int lbound(const int* a, int n, int key) {
  int lo = 0, hi = n;
  while (lo < hi) {
    int mid = (lo + hi) >> 1;
    if (a[mid] < key) lo = mid + 1; else hi = mid;
  }
  return lo;
}

__global__ void k_final(const float* __restrict__ gsum, const int* __restrict__ batch,
                        const float* __restrict__ fcW, const float* __restrict__ fcb,
                        float* __restrict__ out, int n_nodes, int num_graphs) {
  int g = blockIdx.x * blockDim.x + threadIdx.x;
  if (g >= num_graphs) return;
  int lo = lbound(batch, n_nodes, g);
  int hi = lbound(batch, n_nodes, g + 1);
  float cnt = (float)(hi - lo);
  float inv = 1.0f / fmaxf(cnt, 1.0f);
  float gv[16];
#pragma unroll
  for (int c = 0; c < 16; ++c) gv[c] = gsum[(size_t)g * 16 + c] * inv;
  float o[16];
#pragma unroll
  for (int c = 0; c < 16; ++c) o[c] = fcb[c];
#pragma unroll
  for (int k = 0; k < 16; ++k) {
    float gk = gv[k];
    const float* w = fcW + k * 16;
#pragma unroll
    for (int c = 0; c < 16; ++c) o[c] = fmaf(gk, w[c], o[c]);
  }
#pragma unroll
  for (int c = 0; c < 16; ++c) out[(size_t)g * 16 + c] = o[c];
}

extern "C" void kernel_launch(void* const* d_in, const int* in_sizes, int n_in,
                              void* d_out, int out_size, void* d_ws, size_t ws_size,
                              hipStream_t stream) {
  const float* x   = (const float*)d_in[0];
  const float* W1  = (const float*)d_in[1];
  const float* b1  = (const float*)d_in[2];
  const float* W2  = (const float*)d_in[3];
  const float* b2  = (const float*)d_in[4];
  const float* fcW = (const float*)d_in[5];
  const float* fcb = (const float*)d_in[6];
  const int* ei    = (const int*)d_in[7];
  const int* batch = (const int*)d_in[8];

  const int IN_CH = 128, HID = 16, NCLS = 16;
  int n_nodes = in_sizes[0] / IN_CH;       // 200000
  int E = in_sizes[7] / 2;                 // 6400000
  int num_graphs = out_size / NCLS;        // 512
  const int* src = ei;
  const int* dst = ei + E;
  int nbuck = (n_nodes + BNODES - 1) >> BSH;  // 391 (<= 512 assumed)
  size_t seg_elems = (size_t)nbuck * CAP;     // segmented capacity

  // workspace: region aliases {bucketed} then {H1, H2}; edges2 separate (lives
  // until the end, same slot size as the old csr).
  char* ws = (char*)d_ws;
  size_t h_bytes = sizeof(_Float16) * (size_t)n_nodes * 16;  // 6.4 MB each
  size_t region_bytes = 2 * h_bytes;
  if (sizeof(unsigned) * seg_elems > region_bytes)
    region_bytes = sizeof(unsigned) * seg_elems;
  unsigned* bucketed = (unsigned*)ws;
  _Float16* H1  = (_Float16*)ws;
  _Float16* H2  = (_Float16*)(ws + h_bytes);
  ws += region_bytes;
  unsigned* edges2 = (unsigned*)ws; ws += sizeof(unsigned) * seg_elems;
  float* dinv = (float*)ws; ws += sizeof(float) * (size_t)n_nodes;
  int*   gpos = (int*)ws;   ws += sizeof(int) * 1056;
  float* gsum = (float*)ws;

  int gn  = (n_nodes + TPB - 1) / TPB;
  int gg  = (num_graphs + TPB - 1) / TPB;
  int gs  = (E + STILE - 1) / STILE;           // tiles for k_scat
  int gi  = ((nbuck > num_graphs * HID ? nbuck : num_graphs * HID) + TPB - 1) / TPB;

  k_init <<<gi, TPB, 0, stream>>>(gpos, gsum, nbuck, num_graphs * HID);
  k_scat <<<gs, SCAT_TPB, 0, stream>>>(src, dst, gpos, bucketed, E, nbuck);
  k_tile <<<nbuck, ACC_TPB, 0, stream>>>(bucketed, gpos, edges2, dinv, n_nodes);
  k_xw1  <<<gn, TPB, 0, stream>>>(x, W1, dinv, H1, n_nodes);
  k_acc1 <<<nbuck, ACC_TPB, 0, stream>>>(H1, edges2, gpos, dinv, b1, W2, H2, n_nodes);
  k_acc2 <<<nbuck, ACC_TPB, 0, stream>>>(H2, edges2, gpos, dinv, b2, batch, gsum, n_nodes);
  k_final<<<gg, TPB, 0, stream>>>(gsum, batch, fcW, fcb, (float*)d_out,
                                  n_nodes, num_graphs);
}

// Round 7
// 237.816 us; speedup vs baseline: 6.4285x; 6.4285x over previous
//
#include <hip/hip_runtime.h>

#define TPB 256
#define BSH 9                   // log2(nodes per bucket)
#define BNODES (1 << BSH)       // 512
#define BMASK (BNODES - 1)
#define SCAT_TPB 1024
#define STILE 16384             // edges per k_scat tile (64 KB stage)
#define EPT 16                  // edges per thread in k_scat (STILE/SCAT_TPB)
#define SORT_TPB 1024
#define QCAP 12288              // LDS stage entries for one half-bucket (48 KB)
#define CAP 18432               // bucket segment capacity (mean 16384, +16 sigma)

typedef _Float16 half8 __attribute__((ext_vector_type(8)));
typedef _Float16 half2v __attribute__((ext_vector_type(2)));

// ---------------- init: gpos[b] = b*CAP, gsum = 0 ----------------
__global__ void k_init(int* __restrict__ gpos, float* __restrict__ gsum,
                       int nbuck, int gsum_len) {
  int i = blockIdx.x * blockDim.x + threadIdx.x;
  if (i < nbuck) gpos[i] = i * CAP;
  if (i < gsum_len) gsum[i] = 0.0f;
}

// ---------------- tile-sort scatter into segmented buckets ----------------
__global__ void __launch_bounds__(SCAT_TPB)
k_scat(const int* __restrict__ src, const int* __restrict__ dst,
       int* __restrict__ gpos, unsigned* __restrict__ bucketed,
       int E, int nbuck) {
  __shared__ unsigned stage[STILE];   // 64 KB, bucket-sorted tile
  __shared__ int cnt[512];
  __shared__ int runp[512];
  __shared__ int lofs[513];
  __shared__ int base[512];
  __shared__ int wsum[16];
  int t = threadIdx.x;
  int ts = blockIdx.x * STILE;
  int count = min(STILE, E - ts);
  int d[EPT], s[EPT];

  for (int i = t; i < nbuck; i += SCAT_TPB) cnt[i] = 0;
  __syncthreads();
  // pass A: load tile into registers + count
#pragma unroll
  for (int j = 0; j < EPT; ++j) {
    int i = j * SCAT_TPB + t;
    if (i < count) {
      d[j] = dst[ts + i];
      s[j] = src[ts + i];
      atomicAdd(&cnt[d[j] >> BSH], 1);
    }
  }
  __syncthreads();
  // scan + global reservation (one atomic per non-empty bucket)
  {
    int v = (t < nbuck) ? cnt[t] : 0;
    int lane = t & 63, wid = t >> 6;
    int inc = v;
    for (int dd = 1; dd < 64; dd <<= 1) {
      int u = __shfl_up(inc, dd, 64);
      if (lane >= dd) inc += u;
    }
    if (lane == 63) wsum[wid] = inc;
    __syncthreads();
    int woff = 0;
    for (int w = 0; w < wid; ++w) woff += wsum[w];
    int excl = woff + inc - v;
    if (t < nbuck) {
      lofs[t] = excl;
      runp[t] = excl;
      base[t] = v ? atomicAdd(&gpos[t], v) : 0;
    }
    if (t == 0) lofs[nbuck] = count;
  }
  __syncthreads();
  // pass B: place registers into stage (bucket-sorted)
#pragma unroll
  for (int j = 0; j < EPT; ++j) {
    int i = j * SCAT_TPB + t;
    if (i < count) {
      int b = d[j] >> BSH;
      int p = atomicAdd(&runp[b], 1);
      stage[p] = ((unsigned)(d[j] & BMASK) << 18) | (unsigned)s[j];
    }
  }
  __syncthreads();
  // pass C: per-wave bucket-run copy (sequential stage reads / global writes)
  {
    int lane = t & 63, wid = t >> 6;
    for (int b = wid; b < nbuck; b += SCAT_TPB / 64) {
      int s0 = lofs[b], s1 = lofs[b + 1];
      int gb = base[b];
      for (int i = s0 + lane; i < s1; i += 64)
        bucketed[gb + (i - s0)] = stage[i];
    }
  }
}

// ---------------- per-bucket node sort: off/endo, dinv, half-staged csr ----------------
// 1 count pass + 2 half passes (256 nodes each) over the bucket segment.
__global__ void __launch_bounds__(SORT_TPB)
k_sortb(const unsigned* __restrict__ bucketed, const int* __restrict__ gpos,
        int* __restrict__ csr, int* __restrict__ off, int* __restrict__ endo,
        float* __restrict__ dinv, int N) {
  int b = blockIdx.x;
  int t = threadIdx.x;
  int n0 = b << BSH;
  int beg = b * CAP;
  int end = gpos[b];
  int total = end - beg;
  __shared__ int cntT[BNODES];
  __shared__ int run[BNODES];       // bucket-relative running positions
  __shared__ int wsum[16];
  __shared__ unsigned stage[QCAP];  // 48 KB
  __shared__ int qinfo[2];
  if (t < BNODES) cntT[t] = 0;
  __syncthreads();
  for (int i = beg + t; i < end; i += SORT_TPB) {
    unsigned p = bucketed[i];
    atomicAdd(&cntT[(p >> 18) & BMASK], 1);
  }
  __syncthreads();
  int v = (t < BNODES) ? cntT[t] : 0;
  int lane = t & 63, wid = t >> 6;
  int inc = v;
  for (int d = 1; d < 64; d <<= 1) {
    int u = __shfl_up(inc, d, 64);
    if (lane >= d) inc += u;
  }
  if (lane == 63) wsum[wid] = inc;
  __syncthreads();
  int woff = 0;
  for (int w = 0; w < wid; ++w) woff += wsum[w];
  int excl = woff + inc - v;
  if (t < BNODES) {
    run[t] = excl;
    int n = n0 + t;
    if (n < N) {
      off[n] = beg + excl;
      endo[n] = beg + excl + v;
      dinv[n] = rsqrtf((float)v + 1.0f);
    }
  }
  __syncthreads();
  // two half passes: place 256 nodes' edges into LDS, stream out coalesced
  for (int q = 0; q < 2; ++q) {
    if (t == 0) {
      qinfo[0] = run[q << 8];                          // half start (unmutated)
      qinfo[1] = (q == 0) ? run[1 << 8] : total;       // half end
    }
    __syncthreads();
    int qs = qinfo[0];
    int qcnt = qinfo[1] - qs;
    for (int i = beg + t; i < end; i += SORT_TPB) {
      unsigned p = bucketed[i];
      int idx = (p >> 18) & BMASK;
      if ((idx >> 8) == q) {
        int r = atomicAdd(&run[idx], 1);
        int pos = r - qs;
        if (pos < QCAP) stage[pos] = p & 0x3ffffu;
        else csr[beg + r] = (int)(p & 0x3ffffu);  // overflow fallback (rare)
      }
    }
    __syncthreads();
    int lim = qcnt < QCAP ? qcnt : QCAP;
    for (int i = t; i < lim; i += SORT_TPB)
      csr[beg + qs + i] = (int)stage[i];
    __syncthreads();
  }
}

// ---------------- hs1 = fp16( dinv * (x @ W1) ) ----------------
__global__ void k_xw1(const float* __restrict__ x, const float* __restrict__ W1,
                      const float* __restrict__ dinv, _Float16* __restrict__ hs,
                      int n_nodes) {
  int n = blockIdx.x * blockDim.x + threadIdx.x;
  if (n >= n_nodes) return;
  const float4* xr = reinterpret_cast<const float4*>(x + (size_t)n * 128);
  float s[16];
#pragma unroll
  for (int c = 0; c < 16; ++c) s[c] = 0.0f;
#pragma unroll 4
  for (int k4 = 0; k4 < 32; ++k4) {
    float4 xv = xr[k4];
    const float* w = W1 + k4 * 64;  // uniform address -> scalar loads
#pragma unroll
    for (int c = 0; c < 16; ++c) s[c] = fmaf(xv.x, w[c], s[c]);
#pragma unroll
    for (int c = 0; c < 16; ++c) s[c] = fmaf(xv.y, w[16 + c], s[c]);
#pragma unroll
    for (int c = 0; c < 16; ++c) s[c] = fmaf(xv.z, w[32 + c], s[c]);
#pragma unroll
    for (int c = 0; c < 16; ++c) s[c] = fmaf(xv.w, w[48 + c], s[c]);
  }
  float dn = dinv[n];
  half8 v0, v1;
#pragma unroll
  for (int j = 0; j < 8; ++j) v0[j] = (_Float16)(dn * s[j]);
#pragma unroll
  for (int j = 0; j < 8; ++j) v1[j] = (_Float16)(dn * s[8 + j]);
  half8* hp = reinterpret_cast<half8*>(hs + (size_t)n * 16);
  hp[0] = v0;
  hp[1] = v1;
}

// ---------------- 8-lane gather: deep-batched, index-prefetched ----------------
__device__ __forceinline__ void gather2(const _Float16* __restrict__ tab,
                                        const int* __restrict__ csr,
                                        int beg, int end, int c2,
                                        float& a0, float& a1) {
  int i = beg;
  int n16 = (end - beg) >> 4;
  if (n16 > 0) {
    int idx[16];
#pragma unroll
    for (int j = 0; j < 16; ++j) idx[j] = csr[i + j];
    for (int it = 1; it < n16; ++it) {
      half2v f[16];
#pragma unroll
      for (int j = 0; j < 16; ++j)
        f[j] = *reinterpret_cast<const half2v*>(tab + (size_t)idx[j] * 16 + c2 * 2);
      // prefetch next batch of indices while table loads are in flight
#pragma unroll
      for (int j = 0; j < 16; ++j) idx[j] = csr[i + 16 + j];
#pragma unroll
      for (int j = 0; j < 16; ++j) { a0 += (float)f[j][0]; a1 += (float)f[j][1]; }
      i += 16;
    }
    // drain the last prefetched batch
    half2v f[16];
#pragma unroll
    for (int j = 0; j < 16; ++j)
      f[j] = *reinterpret_cast<const half2v*>(tab + (size_t)idx[j] * 16 + c2 * 2);
#pragma unroll
    for (int j = 0; j < 16; ++j) { a0 += (float)f[j][0]; a1 += (float)f[j][1]; }
    i += 16;
  }
  if (i + 8 <= end) {
    int idx8[8];
    half2v f[8];
#pragma unroll
    for (int j = 0; j < 8; ++j) idx8[j] = csr[i + j];
#pragma unroll
    for (int j = 0; j < 8; ++j)
      f[j] = *reinterpret_cast<const half2v*>(tab + (size_t)idx8[j] * 16 + c2 * 2);
#pragma unroll
    for (int j = 0; j < 8; ++j) { a0 += (float)f[j][0]; a1 += (float)f[j][1]; }
    i += 8;
  }
  for (; i < end; ++i) {
    int idx = csr[i];
    half2v f = *reinterpret_cast<const half2v*>(tab + (size_t)idx * 16 + c2 * 2);
    a0 += (float)f[0];
    a1 += (float)f[1];
  }
}

// ---------------- gather conv1 + relu + W2 transform (8 lanes/node) ----------------
__global__ void k_gc1(const _Float16* __restrict__ hs1, const int* __restrict__ off,
                      const int* __restrict__ endo, const int* __restrict__ csr,
                      const float* __restrict__ dinv, const float* __restrict__ b1,
                      const float* __restrict__ W2, _Float16* __restrict__ hs2, int N) {
  int t = blockIdx.x * blockDim.x + threadIdx.x;
  int n = t >> 3, c2 = t & 7;
  if (n >= N) return;
  half2v selfr = *reinterpret_cast<const half2v*>(hs1 + (size_t)n * 16 + c2 * 2);
  float a0 = (float)selfr[0], a1 = (float)selfr[1];
  gather2(hs1, csr, off[n], endo[n], c2, a0, a1);
  float dn = dinv[n];
  float h1a = fmaxf(fmaf(dn, a0, b1[c2 * 2 + 0]), 0.0f);
  float h1b = fmaxf(fmaf(dn, a1, b1[c2 * 2 + 1]), 0.0f);
  float oa = 0.0f, ob = 0.0f;
#pragma unroll
  for (int j = 0; j < 8; ++j) {
    float hk0 = __shfl(h1a, j, 8);  // h1[2j]
    float hk1 = __shfl(h1b, j, 8);  // h1[2j+1]
    oa = fmaf(hk0, W2[(2 * j) * 16 + c2 * 2 + 0], oa);
    ob = fmaf(hk0, W2[(2 * j) * 16 + c2 * 2 + 1], ob);
    oa = fmaf(hk1, W2[(2 * j + 1) * 16 + c2 * 2 + 0], oa);
    ob = fmaf(hk1, W2[(2 * j + 1) * 16 + c2 * 2 + 1], ob);
  }
  half2v outv;
  outv[0] = (_Float16)(dn * oa);
  outv[1] = (_Float16)(dn * ob);
  *reinterpret_cast<half2v*>(hs2 + (size_t)n * 16 + c2 * 2) = outv;
}

// ---------------- gather conv2 + bias + pool accumulate (8 lanes/node) ----------------
__global__ void k_gc2(const _Float16* __restrict__ hs2, const int* __restrict__ off,
                      const int* __restrict__ endo, const int* __restrict__ csr,
                      const float* __restrict__ dinv, const float* __restrict__ b2,
                      const int* __restrict__ batch, float* __restrict__ gsum, int N) {
  int t = threadIdx.x;
  int n = blockIdx.x * 32 + (t >> 3);
  int c2 = t & 7;
  float v0 = 0.0f, v1 = 0.0f;
  int g = 0;
  if (n < N) {
    half2v selfr = *reinterpret_cast<const half2v*>(hs2 + (size_t)n * 16 + c2 * 2);
    float a0 = (float)selfr[0], a1 = (float)selfr[1];
    gather2(hs2, csr, off[n], endo[n], c2, a0, a1);
    float dn = dinv[n];
    v0 = fmaf(dn, a0, b2[c2 * 2 + 0]);
    v1 = fmaf(dn, a1, b2[c2 * 2 + 1]);
    g = batch[n];
  }
  // block covers 32 consecutive nodes; batch is sorted -> usually one graph
  __shared__ float2 red[256];
  __shared__ int sg[2];
  int nfirst = blockIdx.x * 32;
  int nlast = min(nfirst + 31, N - 1);
  if (t == 0) sg[0] = batch[nfirst];
  if (t == 255) sg[1] = batch[nlast];
  __syncthreads();
  bool uniform = (sg[0] == sg[1]);
  if (uniform) {
    red[t] = make_float2(v0, v1);
    __syncthreads();
#pragma unroll
    for (int s2 = 16; s2 > 0; s2 >>= 1) {
      if ((t >> 3) < s2) {
        float2 a = red[t], b = red[t + s2 * 8];
        red[t] = make_float2(a.x + b.x, a.y + b.y);
      }
      __syncthreads();
    }
    if (t < 8) {
      float2 r = red[t];
      unsafeAtomicAdd(&gsum[(size_t)sg[0] * 16 + t * 2 + 0], r.x);
      unsafeAtomicAdd(&gsum[(size_t)sg[0] * 16 + t * 2 + 1], r.y);
    }
  } else if (n < N) {
    unsafeAtomicAdd(&gsum[(size_t)g * 16 + c2 * 2 + 0], v0);
    unsafeAtomicAdd(&gsum[(size_t)g * 16 + c2 * 2 + 1], v1);
  }
}

// ---------------- mean + FC head ----------------
__device__ __forceinline__ int lbound(const int* a, int n, int key) {
  int lo = 0, hi = n;
  while (lo < hi) {
    int mid = (lo + hi) >> 1;
    if (a[mid] < key) lo = mid + 1; else hi = mid;
  }
  return lo;
}

__global__ void k_final(const float* __restrict__ gsum, const int* __restrict__ batch,
                        const float* __restrict__ fcW, const float* __restrict__ fcb,
                        float* __restrict__ out, int n_nodes, int num_graphs) {
  int g = blockIdx.x * blockDim.x + threadIdx.x;
  if (g >= num_graphs) return;
  int lo = lbound(batch, n_nodes, g);
  int hi = lbound(batch, n_nodes, g + 1);
  float cnt = (float)(hi - lo);
  float inv = 1.0f / fmaxf(cnt, 1.0f);
  float gv[16];
#pragma unroll
  for (int c = 0; c < 16; ++c) gv[c] = gsum[(size_t)g * 16 + c] * inv;
  float o[16];
#pragma unroll
  for (int c = 0; c < 16; ++c) o[c] = fcb[c];
#pragma unroll
  for (int k = 0; k < 16; ++k) {
    float gk = gv[k];
    const float* w = fcW + k * 16;
#pragma unroll
    for (int c = 0; c < 16; ++c) o[c] = fmaf(gk, w[c], o[c]);
  }
#pragma unroll
  for (int c = 0; c < 16; ++c) out[(size_t)g * 16 + c] = o[c];
}

extern "C" void kernel_launch(void* const* d_in, const int* in_sizes, int n_in,
                              void* d_out, int out_size, void* d_ws, size_t ws_size,
                              hipStream_t stream) {
  const float* x   = (const float*)d_in[0];
  const float* W1  = (const float*)d_in[1];
  const float* b1  = (const float*)d_in[2];
  const float* W2  = (const float*)d_in[3];
  const float* b2  = (const float*)d_in[4];
  const float* fcW = (const float*)d_in[5];
  const float* fcb = (const float*)d_in[6];
  const int* ei    = (const int*)d_in[7];
  const int* batch = (const int*)d_in[8];

  const int IN_CH = 128, HID = 16, NCLS = 16;
  int n_nodes = in_sizes[0] / IN_CH;       // 200000
  int E = in_sizes[7] / 2;                 // 6400000
  int num_graphs = out_size / NCLS;        // 512
  const int* src = ei;
  const int* dst = ei + E;
  int nbuck = (n_nodes + BNODES - 1) >> BSH;  // 391 (<= 512 assumed)
  size_t seg_elems = (size_t)nbuck * CAP;     // segmented capacity

  // workspace: region aliases {bucketed} then {H1, H2}; csr separate.
  char* ws = (char*)d_ws;
  size_t h_bytes = sizeof(_Float16) * (size_t)n_nodes * 16;  // 6.4 MB each
  size_t region_bytes = 2 * h_bytes;
  if (sizeof(unsigned) * seg_elems > region_bytes)
    region_bytes = sizeof(unsigned) * seg_elems;
  unsigned* bucketed = (unsigned*)ws;
  _Float16* H1  = (_Float16*)ws;
  _Float16* H2  = (_Float16*)(ws + h_bytes);
  ws += region_bytes;
  int*   csr  = (int*)ws;   ws += sizeof(int) * seg_elems;
  int*   off  = (int*)ws;   ws += sizeof(int) * ((size_t)n_nodes + 64);
  int*   endo = (int*)ws;   ws += sizeof(int) * ((size_t)n_nodes + 64);
  float* dinv = (float*)ws; ws += sizeof(float) * (size_t)n_nodes;
  int*   gpos = (int*)ws;   ws += sizeof(int) * 1056;
  float* gsum = (float*)ws;

  int gn  = (n_nodes + TPB - 1) / TPB;
  int gg  = (num_graphs + TPB - 1) / TPB;
  int gnc = ((n_nodes * 8) + TPB - 1) / TPB;   // gather conv1: 8 lanes/node
  int gb  = (n_nodes + 31) / 32;               // k_gc2: 32 nodes/block
  int gs  = (E + STILE - 1) / STILE;           // tiles for k_scat
  int gi  = ((nbuck > num_graphs * HID ? nbuck : num_graphs * HID) + TPB - 1) / TPB;

  k_init <<<gi, TPB, 0, stream>>>(gpos, gsum, nbuck, num_graphs * HID);
  k_scat <<<gs, SCAT_TPB, 0, stream>>>(src, dst, gpos, bucketed, E, nbuck);
  k_sortb<<<nbuck, SORT_TPB, 0, stream>>>(bucketed, gpos, csr, off, endo,
                                          dinv, n_nodes);
  k_xw1  <<<gn, TPB, 0, stream>>>(x, W1, dinv, H1, n_nodes);
  k_gc1  <<<gnc, TPB, 0, stream>>>(H1, off, endo, csr, dinv, b1, W2, H2, n_nodes);
  k_gc2  <<<gb, TPB, 0, stream>>>(H2, off, endo, csr, dinv, b2, batch, gsum, n_nodes);
  k_final<<<gg, TPB, 0, stream>>>(gsum, batch, fcW, fcb, (float*)d_out,
                                  n_nodes, num_graphs);
}

// Round 8
// 232.357 us; speedup vs baseline: 6.5795x; 1.0235x over previous
//
#include <hip/hip_runtime.h>

#define TPB 256
#define BSH 9                   // log2(nodes per bucket)
#define BNODES (1 << BSH)       // 512
#define BMASK (BNODES - 1)
#define SCAT_TPB 1024
#define STILE 16384             // edges per k_scat tile (64 KB stage)
#define EPT 16                  // edges per thread in k_scat (STILE/SCAT_TPB)
#define SORT_TPB 1024
#define CAP 18432               // bucket segment capacity (mean 16384, +16 sigma)

typedef _Float16 half8 __attribute__((ext_vector_type(8)));
typedef _Float16 half2v __attribute__((ext_vector_type(2)));

// ---------------- init: gpos[b] = b*CAP, gsum = 0 ----------------
__global__ void k_init(int* __restrict__ gpos, float* __restrict__ gsum,
                       int nbuck, int gsum_len) {
  int i = blockIdx.x * blockDim.x + threadIdx.x;
  if (i < nbuck) gpos[i] = i * CAP;
  if (i < gsum_len) gsum[i] = 0.0f;
}

// ---------------- tile-sort scatter into segmented buckets ----------------
__global__ void __launch_bounds__(SCAT_TPB)
k_scat(const int* __restrict__ src, const int* __restrict__ dst,
       int* __restrict__ gpos, unsigned* __restrict__ bucketed,
       int E, int nbuck) {
  __shared__ unsigned stage[STILE];   // 64 KB, bucket-sorted tile
  __shared__ int cnt[512];
  __shared__ int runp[512];
  __shared__ int lofs[513];
  __shared__ int base[512];
  __shared__ int wsum[16];
  int t = threadIdx.x;
  int ts = blockIdx.x * STILE;
  int count = min(STILE, E - ts);
  int d[EPT], s[EPT];

  for (int i = t; i < nbuck; i += SCAT_TPB) cnt[i] = 0;
  __syncthreads();
  // pass A: load tile into registers + count
#pragma unroll
  for (int j = 0; j < EPT; ++j) {
    int i = j * SCAT_TPB + t;
    if (i < count) {
      d[j] = dst[ts + i];
      s[j] = src[ts + i];
      atomicAdd(&cnt[d[j] >> BSH], 1);
    }
  }
  __syncthreads();
  // scan + global reservation (one atomic per non-empty bucket)
  {
    int v = (t < nbuck) ? cnt[t] : 0;
    int lane = t & 63, wid = t >> 6;
    int inc = v;
    for (int dd = 1; dd < 64; dd <<= 1) {
      int u = __shfl_up(inc, dd, 64);
      if (lane >= dd) inc += u;
    }
    if (lane == 63) wsum[wid] = inc;
    __syncthreads();
    int woff = 0;
    for (int w = 0; w < wid; ++w) woff += wsum[w];
    int excl = woff + inc - v;
    if (t < nbuck) {
      lofs[t] = excl;
      runp[t] = excl;
      base[t] = v ? atomicAdd(&gpos[t], v) : 0;
    }
    if (t == 0) lofs[nbuck] = count;
  }
  __syncthreads();
  // pass B: place registers into stage (bucket-sorted)
#pragma unroll
  for (int j = 0; j < EPT; ++j) {
    int i = j * SCAT_TPB + t;
    if (i < count) {
      int b = d[j] >> BSH;
      int p = atomicAdd(&runp[b], 1);
      stage[p] = ((unsigned)(d[j] & BMASK) << 18) | (unsigned)s[j];
    }
  }
  __syncthreads();
  // pass C: per-wave bucket-run copy (sequential stage reads / global writes)
  {
    int lane = t & 63, wid = t >> 6;
    for (int b = wid; b < nbuck; b += SCAT_TPB / 64) {
      int s0 = lofs[b], s1 = lofs[b + 1];
      int gb = base[b];
      for (int i = s0 + lane; i < s1; i += 64)
        bucketed[gb + (i - s0)] = stage[i];
    }
  }
}

// ---------------- per-bucket node sort: off/endo, dinv, full-bucket-staged csr ----------------
// 1 count pass + 1 scatter pass (whole bucket staged in 72 KB LDS; gfx950
// allows >64 KB static LDS per workgroup). 2 blocks/CU (wave-capped anyway).
__global__ void __launch_bounds__(SORT_TPB)
k_sortb(const unsigned* __restrict__ bucketed, const int* __restrict__ gpos,
        int* __restrict__ csr, int* __restrict__ off, int* __restrict__ endo,
        float* __restrict__ dinv, int N) {
  int b = blockIdx.x;
  int t = threadIdx.x;
  int n0 = b << BSH;
  int beg = b * CAP;
  int end = gpos[b];
  int total = end - beg;
  __shared__ int cntT[BNODES];
  __shared__ int run[BNODES];        // bucket-relative running positions
  __shared__ int wsum[16];
  __shared__ unsigned stage[CAP];    // 72 KB — whole bucket
  if (t < BNODES) cntT[t] = 0;
  __syncthreads();
  for (int i = beg + t; i < end; i += SORT_TPB) {
    unsigned p = bucketed[i];
    atomicAdd(&cntT[(p >> 18) & BMASK], 1);
  }
  __syncthreads();
  int v = (t < BNODES) ? cntT[t] : 0;
  int lane = t & 63, wid = t >> 6;
  int inc = v;
  for (int d = 1; d < 64; d <<= 1) {
    int u = __shfl_up(inc, d, 64);
    if (lane >= d) inc += u;
  }
  if (lane == 63) wsum[wid] = inc;
  __syncthreads();
  int woff = 0;
  for (int w = 0; w < wid; ++w) woff += wsum[w];
  int excl = woff + inc - v;
  if (t < BNODES) {
    run[t] = excl;
    int n = n0 + t;
    if (n < N) {
      off[n] = beg + excl;
      endo[n] = beg + excl + v;
      dinv[n] = rsqrtf((float)v + 1.0f);
    }
  }
  __syncthreads();
  // single scatter pass: place every edge's src into its node-grouped slot
  for (int i = beg + t; i < end; i += SORT_TPB) {
    unsigned p = bucketed[i];
    int idx = (p >> 18) & BMASK;
    int r = atomicAdd(&run[idx], 1);
    stage[r] = p & 0x3ffffu;
  }
  __syncthreads();
  // stream out coalesced
  for (int i = t; i < total; i += SORT_TPB)
    csr[beg + i] = (int)stage[i];
}

// ---------------- hs1 = fp16( dinv * (x @ W1) ) ----------------
__global__ void k_xw1(const float* __restrict__ x, const float* __restrict__ W1,
                      const float* __restrict__ dinv, _Float16* __restrict__ hs,
                      int n_nodes) {
  int n = blockIdx.x * blockDim.x + threadIdx.x;
  if (n >= n_nodes) return;
  const float4* xr = reinterpret_cast<const float4*>(x + (size_t)n * 128);
  float s[16];
#pragma unroll
  for (int c = 0; c < 16; ++c) s[c] = 0.0f;
#pragma unroll 4
  for (int k4 = 0; k4 < 32; ++k4) {
    float4 xv = xr[k4];
    const float* w = W1 + k4 * 64;  // uniform address -> scalar loads
#pragma unroll
    for (int c = 0; c < 16; ++c) s[c] = fmaf(xv.x, w[c], s[c]);
#pragma unroll
    for (int c = 0; c < 16; ++c) s[c] = fmaf(xv.y, w[16 + c], s[c]);
#pragma unroll
    for (int c = 0; c < 16; ++c) s[c] = fmaf(xv.z, w[32 + c], s[c]);
#pragma unroll
    for (int c = 0; c < 16; ++c) s[c] = fmaf(xv.w, w[48 + c], s[c]);
  }
  float dn = dinv[n];
  half8 v0, v1;
#pragma unroll
  for (int j = 0; j < 8; ++j) v0[j] = (_Float16)(dn * s[j]);
#pragma unroll
  for (int j = 0; j < 8; ++j) v1[j] = (_Float16)(dn * s[8 + j]);
  half8* hp = reinterpret_cast<half8*>(hs + (size_t)n * 16);
  hp[0] = v0;
  hp[1] = v1;
}

// ---------------- 8-lane gather: deep-batched, index-prefetched ----------------
__device__ __forceinline__ void gather2(const _Float16* __restrict__ tab,
                                        const int* __restrict__ csr,
                                        int beg, int end, int c2,
                                        float& a0, float& a1) {
  int i = beg;
  int n16 = (end - beg) >> 4;
  if (n16 > 0) {
    int idx[16];
#pragma unroll
    for (int j = 0; j < 16; ++j) idx[j] = csr[i + j];
    for (int it = 1; it < n16; ++it) {
      half2v f[16];
#pragma unroll
      for (int j = 0; j < 16; ++j)
        f[j] = *reinterpret_cast<const half2v*>(tab + (size_t)idx[j] * 16 + c2 * 2);
      // prefetch next batch of indices while table loads are in flight
#pragma unroll
      for (int j = 0; j < 16; ++j) idx[j] = csr[i + 16 + j];
#pragma unroll
      for (int j = 0; j < 16; ++j) { a0 += (float)f[j][0]; a1 += (float)f[j][1]; }
      i += 16;
    }
    // drain the last prefetched batch
    half2v f[16];
#pragma unroll
    for (int j = 0; j < 16; ++j)
      f[j] = *reinterpret_cast<const half2v*>(tab + (size_t)idx[j] * 16 + c2 * 2);
#pragma unroll
    for (int j = 0; j < 16; ++j) { a0 += (float)f[j][0]; a1 += (float)f[j][1]; }
    i += 16;
  }
  if (i + 8 <= end) {
    int idx8[8];
    half2v f[8];
#pragma unroll
    for (int j = 0; j < 8; ++j) idx8[j] = csr[i + j];
#pragma unroll
    for (int j = 0; j < 8; ++j)
      f[j] = *reinterpret_cast<const half2v*>(tab + (size_t)idx8[j] * 16 + c2 * 2);
#pragma unroll
    for (int j = 0; j < 8; ++j) { a0 += (float)f[j][0]; a1 += (float)f[j][1]; }
    i += 8;
  }
  for (; i < end; ++i) {
    int idx = csr[i];
    half2v f = *reinterpret_cast<const half2v*>(tab + (size_t)idx * 16 + c2 * 2);
    a0 += (float)f[0];
    a1 += (float)f[1];
  }
}

// ---------------- gather conv1 + relu + W2 transform (8 lanes/node) ----------------
__global__ void k_gc1(const _Float16* __restrict__ hs1, const int* __restrict__ off,
                      const int* __restrict__ endo, const int* __restrict__ csr,
                      const float* __restrict__ dinv, const float* __restrict__ b1,
                      const float* __restrict__ W2, _Float16* __restrict__ hs2, int N) {
  int t = blockIdx.x * blockDim.x + threadIdx.x;
  int n = t >> 3, c2 = t & 7;
  if (n >= N) return;
  half2v selfr = *reinterpret_cast<const half2v*>(hs1 + (size_t)n * 16 + c2 * 2);
  float a0 = (float)selfr[0], a1 = (float)selfr[1];
  gather2(hs1, csr, off[n], endo[n], c2, a0, a1);
  float dn = dinv[n];
  float h1a = fmaxf(fmaf(dn, a0, b1[c2 * 2 + 0]), 0.0f);
  float h1b = fmaxf(fmaf(dn, a1, b1[c2 * 2 + 1]), 0.0f);
  float oa = 0.0f, ob = 0.0f;
#pragma unroll
  for (int j = 0; j < 8; ++j) {
    float hk0 = __shfl(h1a, j, 8);  // h1[2j]
    float hk1 = __shfl(h1b, j, 8);  // h1[2j+1]
    oa = fmaf(hk0, W2[(2 * j) * 16 + c2 * 2 + 0], oa);
    ob = fmaf(hk0, W2[(2 * j) * 16 + c2 * 2 + 1], ob);
    oa = fmaf(hk1, W2[(2 * j + 1) * 16 + c2 * 2 + 0], oa);
    ob = fmaf(hk1, W2[(2 * j + 1) * 16 + c2 * 2 + 1], ob);
  }
  half2v outv;
  outv[0] = (_Float16)(dn * oa);
  outv[1] = (_Float16)(dn * ob);
  *reinterpret_cast<half2v*>(hs2 + (size_t)n * 16 + c2 * 2) = outv;
}

// ---------------- gather conv2 + bias + pool accumulate (8 lanes/node) ----------------
__global__ void k_gc2(const _Float16* __restrict__ hs2, const int* __restrict__ off,
                      const int* __restrict__ endo, const int* __restrict__ csr,
                      const float* __restrict__ dinv, const float* __restrict__ b2,
                      const int* __restrict__ batch, float* __restrict__ gsum, int N) {
  int t = threadIdx.x;
  int n = blockIdx.x * 32 + (t >> 3);
  int c2 = t & 7;
  float v0 = 0.0f, v1 = 0.0f;
  int g = 0;
  if (n < N) {
    half2v selfr = *reinterpret_cast<const half2v*>(hs2 + (size_t)n * 16 + c2 * 2);
    float a0 = (float)selfr[0], a1 = (float)selfr[1];
    gather2(hs2, csr, off[n], endo[n], c2, a0, a1);
    float dn = dinv[n];
    v0 = fmaf(dn, a0, b2[c2 * 2 + 0]);
    v1 = fmaf(dn, a1, b2[c2 * 2 + 1]);
    g = batch[n];
  }
  // block covers 32 consecutive nodes; batch is sorted -> usually one graph
  __shared__ float2 red[256];
  __shared__ int sg[2];
  int nfirst = blockIdx.x * 32;
  int nlast = min(nfirst + 31, N - 1);
  if (t == 0) sg[0] = batch[nfirst];
  if (t == 255) sg[1] = batch[nlast];
  __syncthreads();
  bool uniform = (sg[0] == sg[1]);
  if (uniform) {
    red[t] = make_float2(v0, v1);
    __syncthreads();
#pragma unroll
    for (int s2 = 16; s2 > 0; s2 >>= 1) {
      if ((t >> 3) < s2) {
        float2 a = red[t], b = red[t + s2 * 8];
        red[t] = make_float2(a.x + b.x, a.y + b.y);
      }
      __syncthreads();
    }
    if (t < 8) {
      float2 r = red[t];
      unsafeAtomicAdd(&gsum[(size_t)sg[0] * 16 + t * 2 + 0], r.x);
      unsafeAtomicAdd(&gsum[(size_t)sg[0] * 16 + t * 2 + 1], r.y);
    }
  } else if (n < N) {
    unsafeAtomicAdd(&gsum[(size_t)g * 16 + c2 * 2 + 0], v0);
    unsafeAtomicAdd(&gsum[(size_t)g * 16 + c2 * 2 + 1], v1);
  }
}

// ---------------- mean + FC head ----------------
__device__ __forceinline__ int lbound(const int* a, int n, int key) {
  int lo = 0, hi = n;
  while (lo < hi) {
    int mid = (lo + hi) >> 1;
    if (a[mid] < key) lo = mid + 1; else hi = mid;
  }
  return lo;
}

__global__ void k_final(const float* __restrict__ gsum, const int* __restrict__ batch,
                        const float* __restrict__ fcW, const float* __restrict__ fcb,
                        float* __restrict__ out, int n_nodes, int num_graphs) {
  int g = blockIdx.x * blockDim.x + threadIdx.x;
  if (g >= num_graphs) return;
  int lo = lbound(batch, n_nodes, g);
  int hi = lbound(batch, n_nodes, g + 1);
  float cnt = (float)(hi - lo);
  float inv = 1.0f / fmaxf(cnt, 1.0f);
  float gv[16];
#pragma unroll
  for (int c = 0; c < 16; ++c) gv[c] = gsum[(size_t)g * 16 + c] * inv;
  float o[16];
#pragma unroll
  for (int c = 0; c < 16; ++c) o[c] = fcb[c];
#pragma unroll
  for (int k = 0; k < 16; ++k) {
    float gk = gv[k];
    const float* w = fcW + k * 16;
#pragma unroll
    for (int c = 0; c < 16; ++c) o[c] = fmaf(gk, w[c], o[c]);
  }
#pragma unroll
  for (int c = 0; c < 16; ++c) out[(size_t)g * 16 + c] = o[c];
}

extern "C" void kernel_launch(void* const* d_in, const int* in_sizes, int n_in,
                              void* d_out, int out_size, void* d_ws, size_t ws_size,
                              hipStream_t stream) {
  const float* x   = (const float*)d_in[0];
  const float* W1  = (const float*)d_in[1];
  const float* b1  = (const float*)d_in[2];
  const float* W2  = (const float*)d_in[3];
  const float* b2  = (const float*)d_in[4];
  const float* fcW = (const float*)d_in[5];
  const float* fcb = (const float*)d_in[6];
  const int* ei    = (const int*)d_in[7];
  const int* batch = (const int*)d_in[8];

  const int IN_CH = 128, HID = 16, NCLS = 16;
  int n_nodes = in_sizes[0] / IN_CH;       // 200000
  int E = in_sizes[7] / 2;                 // 6400000
  int num_graphs = out_size / NCLS;        // 512
  const int* src = ei;
  const int* dst = ei + E;
  int nbuck = (n_nodes + BNODES - 1) >> BSH;  // 391 (<= 512 assumed)
  size_t seg_elems = (size_t)nbuck * CAP;     // segmented capacity

  // workspace: region aliases {bucketed} then {H1, H2}; csr separate.
  char* ws = (char*)d_ws;
  size_t h_bytes = sizeof(_Float16) * (size_t)n_nodes * 16;  // 6.4 MB each
  size_t region_bytes = 2 * h_bytes;
  if (sizeof(unsigned) * seg_elems > region_bytes)
    region_bytes = sizeof(unsigned) * seg_elems;
  unsigned* bucketed = (unsigned*)ws;
  _Float16* H1  = (_Float16*)ws;
  _Float16* H2  = (_Float16*)(ws + h_bytes);
  ws += region_bytes;
  int*   csr  = (int*)ws;   ws += sizeof(int) * seg_elems;
  int*   off  = (int*)ws;   ws += sizeof(int) * ((size_t)n_nodes + 64);
  int*   endo = (int*)ws;   ws += sizeof(int) * ((size_t)n_nodes + 64);
  float* dinv = (float*)ws; ws += sizeof(float) * (size_t)n_nodes;
  int*   gpos = (int*)ws;   ws += sizeof(int) * 1056;
  float* gsum = (float*)ws;

  int gn  = (n_nodes + TPB - 1) / TPB;
  int gg  = (num_graphs + TPB - 1) / TPB;
  int gnc = ((n_nodes * 8) + TPB - 1) / TPB;   // gather conv1: 8 lanes/node
  int gb  = (n_nodes + 31) / 32;               // k_gc2: 32 nodes/block
  int gs  = (E + STILE - 1) / STILE;           // tiles for k_scat
  int gi  = ((nbuck > num_graphs * HID ? nbuck : num_graphs * HID) + TPB - 1) / TPB;

  k_init <<<gi, TPB, 0, stream>>>(gpos, gsum, nbuck, num_graphs * HID);
  k_scat <<<gs, SCAT_TPB, 0, stream>>>(src, dst, gpos, bucketed, E, nbuck);
  k_sortb<<<nbuck, SORT_TPB, 0, stream>>>(bucketed, gpos, csr, off, endo,
                                          dinv, n_nodes);
  k_xw1  <<<gn, TPB, 0, stream>>>(x, W1, dinv, H1, n_nodes);
  k_gc1  <<<gnc, TPB, 0, stream>>>(H1, off, endo, csr, dinv, b1, W2, H2, n_nodes);
  k_gc2  <<<gb, TPB, 0, stream>>>(H2, off, endo, csr, dinv, b2, batch, gsum, n_nodes);
  k_final<<<gg, TPB, 0, stream>>>(gsum, batch, fcW, fcb, (float*)d_out,
                                  n_nodes, num_graphs);
}